// Round 2
// baseline (574.548 us; speedup 1.0000x reference)
//
#include <hip/hip_runtime.h>
#include <stdint.h>

// B=4096, N=64, C=256, I=128, SUB=4, M=16 pooled keys. All float I/O is fp32.
// Inputs: 0:x(B,64,256) 1:grouped_order(i32) 2:restored_order(unused)
//  3:theta_w(128,256) 4:theta_b(128) 5:phi_w 6:phi_b 7:g_w 8:g_b
//  9:w_w(256,128) 10:w_b(256) 11:bn_gamma(256) 12:bn_beta(256) 13:group_size(unused)
// Internally: bf16 MFMA (16x16x32), fp32 accumulate, fp32 epilogue/output.

typedef __attribute__((ext_vector_type(8))) short  bf16x8; // MFMA A/B frag (4 VGPRs)
typedef __attribute__((ext_vector_type(4))) float  f32x4;  // MFMA C/D frag

// LDS strides (bf16 elements); 16B-aligned rows, worst 2-way bank aliasing (free).
#define XS_S 264   // x tile 64 x 256 (+8 pad)
#define TH_S 136   // theta / y tile 64 x 128 (+8)
#define PH_S 136   // phi_pool 16 x 128 (+8)
#define GX_S 40    // gx_pool^T 128 x 32 (K-padded, cols 16..31 zero) (+8)
#define A_S  40    // attention a 64 x 32 (K-padded) (+8)

__device__ __forceinline__ unsigned short f2bf(float f) {  // RNE fp32->bf16
  union { float ff; uint32_t u; } v; v.ff = f;
  uint32_t r = (v.u + 0x7FFFu + ((v.u >> 16) & 1u)) >> 16;
  return (unsigned short)r;
}
__device__ __forceinline__ float bf2f(unsigned short u) {
  union { uint32_t u; float f; } v; v.u = ((uint32_t)u) << 16;
  return v.f;
}
__device__ __forceinline__ bf16x8 cvt8(const float* __restrict__ p) {
  float4 a = *((const float4*)p);
  float4 b = *((const float4*)(p + 4));
  bf16x8 r;
  r[0] = (short)f2bf(a.x); r[1] = (short)f2bf(a.y);
  r[2] = (short)f2bf(a.z); r[3] = (short)f2bf(a.w);
  r[4] = (short)f2bf(b.x); r[5] = (short)f2bf(b.y);
  r[6] = (short)f2bf(b.z); r[7] = (short)f2bf(b.w);
  return r;
}

// ---- converter: fp32 weights -> bf16 in ws (re-runs every launch) ----------
__global__ void convert_weights(const float* __restrict__ tw, const float* __restrict__ pw,
                                const float* __restrict__ gw, const float* __restrict__ ww,
                                unsigned short* __restrict__ dst) {
  int id = blockIdx.x * 256 + threadIdx.x;      // 0..32767, one float4 each
  const float* srcs[4] = { tw, pw, gw, ww };    // each 32768 fp32
  int arr = id >> 13;                           // 8192 float4 per array
  int off = (id & 8191) * 4;
  float4 v = *((const float4*)(srcs[arr] + off));
  ushort4 o;
  o.x = f2bf(v.x); o.y = f2bf(v.y); o.z = f2bf(v.z); o.w = f2bf(v.w);
  *((ushort4*)(dst + arr * 32768 + off)) = o;
}

// WS=1: bf16 weights from ws; WS=0: fp32 weights from global, cvt on the fly.
template <int WS>
__global__ __launch_bounds__(256, 2) void nonlocal_fused(
    const float* __restrict__ x,
    const int*   __restrict__ go,
    const float* __restrict__ tw, const float* __restrict__ tb,
    const float* __restrict__ pw, const float* __restrict__ pb,
    const float* __restrict__ gw, const float* __restrict__ gb,
    const float* __restrict__ ww, const float* __restrict__ wb,
    const float* __restrict__ bn_g, const float* __restrict__ bn_b,
    const unsigned short* __restrict__ wsw,   // [theta|phi|g|w_w] bf16, 32768 each
    float* __restrict__ out)
{
  __shared__ __align__(16) unsigned short xs [64 * XS_S];  // 33792 B
  __shared__ __align__(16) unsigned short th [64 * TH_S];  // 17408 B (theta, later y)
  __shared__ __align__(16) unsigned short ph [16 * PH_S];  //  4352 B
  __shared__ __align__(16) unsigned short gxt[128 * GX_S]; // 10240 B
  __shared__ __align__(16) unsigned short als[64 * A_S];   //  5120 B
  __shared__ int gos[64];

  const int t    = threadIdx.x;
  const int wave = t >> 6;
  const int lane = t & 63;
  const int l15  = lane & 15;
  const int q    = lane >> 4;          // quad 0..3
  const size_t xbase = (size_t)blockIdx.x * (64 * 256);

  if (t < 64) gos[t] = go[t];

  // ---- zero K-padded buffers (cols >=16 must read as 0 in GEMM3) ----
  {
    uint32_t* z1 = (uint32_t*)als;     // 1280 dwords
    uint32_t* z2 = (uint32_t*)gxt;     // 2560 dwords
    for (int k = t; k < 1280; k += 256) z1[k] = 0u;
    for (int k = t; k < 2560; k += 256) z2[k] = 0u;
  }

  // ---- gather x rows (grouped order), fp32 -> bf16, into LDS ----
  #pragma unroll
  for (int r = 0; r < 8; ++r) {
    int chunk = t + 256 * r;           // 2048 chunks of 8 floats
    int j     = chunk >> 5;            // grouped row 0..63
    int c8    = (chunk & 31) << 3;     // fp32 col, multiple of 8
    int srow  = go[j];
    bf16x8 v = cvt8(x + xbase + (size_t)srow * 256 + c8);
    *((bf16x8*)&xs[j * XS_S + c8]) = v;
  }
  __syncthreads();

  // ================= GEMM1: [theta|phi|gx] = Xg(64x256) . W^T(256x384) ====
  f32x4 acc1[6][4];
  #pragma unroll
  for (int u = 0; u < 6; ++u)
    #pragma unroll
    for (int nt = 0; nt < 4; ++nt)
      acc1[u][nt] = f32x4{0.f, 0.f, 0.f, 0.f};

  #pragma unroll
  for (int kt = 0; kt < 8; ++kt) {
    const int ko = kt * 32 + q * 8;
    bf16x8 a[4];
    #pragma unroll
    for (int nt = 0; nt < 4; ++nt)
      a[nt] = *((const bf16x8*)&xs[(nt * 16 + l15) * XS_S + ko]);
    #pragma unroll
    for (int u = 0; u < 6; ++u) {
      const int iloc = wave * 16 + (u & 1) * 64 + l15;
      bf16x8 bb;
      if (WS) {
        bb = *((const bf16x8*)(wsw + (u >> 1) * 32768 + (size_t)iloc * 256 + ko));
      } else {
        const float* Wf = (u >> 1) == 0 ? tw : ((u >> 1) == 1 ? pw : gw);
        bb = cvt8(Wf + (size_t)iloc * 256 + ko);
      }
      #pragma unroll
      for (int nt = 0; nt < 4; ++nt)
        acc1[u][nt] = __builtin_amdgcn_mfma_f32_16x16x32_bf16(a[nt], bb, acc1[u][nt], 0, 0, 0);
    }
  }

  // ---- bias + (pool) + store to LDS in next-GEMM layouts ----
  const float* Bsel[3] = { tb, pb, gb };
  #pragma unroll
  for (int u = 0; u < 6; ++u) {
    const int s    = u >> 1;                       // 0=theta 1=phi 2=gx
    const int iloc = wave * 16 + (u & 1) * 64 + l15;
    const float bias = Bsel[s][iloc];
    if (s == 0) {
      #pragma unroll
      for (int nt = 0; nt < 4; ++nt)
        #pragma unroll
        for (int r = 0; r < 4; ++r) {
          int j = nt * 16 + q * 4 + r;             // C-layout row = quad*4+reg
          th[j * TH_S + iloc] = f2bf(acc1[u][nt][r] + bias);
        }
    } else {
      #pragma unroll
      for (int nt = 0; nt < 4; ++nt) {
        f32x4 v = acc1[u][nt];
        float pv = fmaxf(fmaxf(v[0], v[1]), fmaxf(v[2], v[3])) + bias; // pool j%4
        int m = nt * 4 + q;                        // pooled key index
        if (s == 1) ph[m * PH_S + iloc] = f2bf(pv);
        else        gxt[iloc * GX_S + m] = f2bf(pv);  // transposed for B-frags
      }
    }
  }
  __syncthreads();

  // ================= GEMM2: f(64x16) = theta . phi_pool^T, K=128 ==========
  f32x4 fac = f32x4{0.f, 0.f, 0.f, 0.f};          // wave owns rows wave*16..+15
  #pragma unroll
  for (int kt = 0; kt < 4; ++kt) {
    const int ko = kt * 32 + q * 8;
    bf16x8 a  = *((const bf16x8*)&th[(wave * 16 + l15) * TH_S + ko]);
    bf16x8 bb = *((const bf16x8*)&ph[l15 * PH_S + ko]);
    fac = __builtin_amdgcn_mfma_f32_16x16x32_bf16(a, bb, fac, 0, 0, 0);
  }

  // ---- softmax over the 16 keys (lanes sharing a quad hold one row) ----
  #pragma unroll
  for (int r = 0; r < 4; ++r) {
    float v  = fac[r];
    float mx = v;
    mx = fmaxf(mx, __shfl_xor(mx, 1));
    mx = fmaxf(mx, __shfl_xor(mx, 2));
    mx = fmaxf(mx, __shfl_xor(mx, 4));
    mx = fmaxf(mx, __shfl_xor(mx, 8));
    float e = __expf(v - mx);
    float sm = e;
    sm += __shfl_xor(sm, 1);
    sm += __shfl_xor(sm, 2);
    sm += __shfl_xor(sm, 4);
    sm += __shfl_xor(sm, 8);
    int j = wave * 16 + q * 4 + r;
    als[j * A_S + l15] = f2bf(e / sm);
  }
  __syncthreads();

  // ================= GEMM3: y(64x128) = a(64x16,Kpad32) . gx_pool =========
  f32x4 y3[8];
  {
    bf16x8 a = *((const bf16x8*)&als[(wave * 16 + l15) * A_S + q * 8]);
    #pragma unroll
    for (int u = 0; u < 8; ++u) {
      bf16x8 bb = *((const bf16x8*)&gxt[(u * 16 + l15) * GX_S + q * 8]);
      f32x4 z = f32x4{0.f, 0.f, 0.f, 0.f};
      y3[u] = __builtin_amdgcn_mfma_f32_16x16x32_bf16(a, bb, z, 0, 0, 0);
    }
  }
  // y -> LDS (reuse theta buffer; theta reads all completed before last barrier)
  #pragma unroll
  for (int u = 0; u < 8; ++u)
    #pragma unroll
    for (int r = 0; r < 4; ++r)
      th[(wave * 16 + q * 4 + r) * TH_S + u * 16 + l15] = f2bf(y3[u][r]);
  __syncthreads();

  // ================= GEMM4: out(64x256) = y(64x128) . w_w^T ===============
  f32x4 acc4[4][4];
  #pragma unroll
  for (int v = 0; v < 4; ++v)
    #pragma unroll
    for (int nt = 0; nt < 4; ++nt)
      acc4[v][nt] = f32x4{0.f, 0.f, 0.f, 0.f};

  #pragma unroll
  for (int kt = 0; kt < 4; ++kt) {
    const int ko = kt * 32 + q * 8;
    bf16x8 a[4];
    #pragma unroll
    for (int nt = 0; nt < 4; ++nt)
      a[nt] = *((const bf16x8*)&th[(nt * 16 + l15) * TH_S + ko]);
    #pragma unroll
    for (int v = 0; v < 4; ++v) {
      const int c = wave * 64 + v * 16 + l15;
      bf16x8 bb;
      if (WS) bb = *((const bf16x8*)(wsw + 3 * 32768 + (size_t)c * 128 + ko));
      else    bb = cvt8(ww + (size_t)c * 128 + ko);
      #pragma unroll
      for (int nt = 0; nt < 4; ++nt)
        acc4[v][nt] = __builtin_amdgcn_mfma_f32_16x16x32_bf16(a[nt], bb, acc4[v][nt], 0, 0, 0);
    }
  }

  // ---- epilogue: (acc + w_b)*gamma/sqrt(1+eps) + beta + x -> fp32 store ---
  // Each quad writes an aligned contiguous 64B line (16 lanes x 4B), row go[j].
  const float rs = rsqrtf(1.0f + 1e-5f);
  #pragma unroll
  for (int v = 0; v < 4; ++v) {
    const int c  = wave * 64 + v * 16 + l15;
    const float wbv = wb[c];
    const float sc  = bn_g[c] * rs;
    const float bt  = bn_b[c];
    #pragma unroll
    for (int nt = 0; nt < 4; ++nt)
      #pragma unroll
      for (int r = 0; r < 4; ++r) {
        int j = nt * 16 + q * 4 + r;
        float xv  = bf2f(xs[j * XS_S + c]);
        float val = (acc4[v][nt][r] + wbv) * sc + bt + xv;
        out[xbase + (size_t)gos[j] * 256 + c] = val;
      }
  }
}

extern "C" void kernel_launch(void* const* d_in, const int* in_sizes, int n_in,
                              void* d_out, int out_size, void* d_ws, size_t ws_size,
                              hipStream_t stream) {
  const float* x  = (const float*)d_in[0];
  const int*   go = (const int*)d_in[1];
  const float* tw = (const float*)d_in[3];
  const float* tb = (const float*)d_in[4];
  const float* pw = (const float*)d_in[5];
  const float* pb = (const float*)d_in[6];
  const float* gw = (const float*)d_in[7];
  const float* gb = (const float*)d_in[8];
  const float* ww = (const float*)d_in[9];
  const float* wb = (const float*)d_in[10];
  const float* bg = (const float*)d_in[11];
  const float* bb = (const float*)d_in[12];
  float* out = (float*)d_out;
  unsigned short* wsw = (unsigned short*)d_ws;

  if (ws_size >= 4u * 32768u * sizeof(unsigned short)) {
    convert_weights<<<dim3(128), dim3(256), 0, stream>>>(tw, pw, gw, ww, wsw);
    nonlocal_fused<1><<<dim3(4096), dim3(256), 0, stream>>>(
        x, go, tw, tb, pw, pb, gw, gb, ww, wb, bg, bb, wsw, out);
  } else {
    nonlocal_fused<0><<<dim3(4096), dim3(256), 0, stream>>>(
        x, go, tw, tb, pw, pb, gw, gb, ww, wb, bg, bb, wsw, out);
  }
}